// Round 13
// baseline (12981.738 us; speedup 1.0000x reference)
//
#include <hip/hip_runtime.h>
#include <hip/hip_fp16.h>

#define TLEN 16384
#define HD 128

typedef _Float16 v8h __attribute__((ext_vector_type(8)));
typedef float    v4f __attribute__((ext_vector_type(4)));

union U4H8 { uint4 u; v8h h; };

__device__ __forceinline__ v8h cvt8(const float* p) {
    v8h r;
    #pragma unroll
    for (int i = 0; i < 8; ++i) r[i] = (_Float16)p[i];
    return r;
}
__device__ __forceinline__ unsigned int packh2(float a, float b) {
    union { _Float16 h[2]; unsigned int u; } c;
    c.h[0] = (_Float16)a; c.h[1] = (_Float16)b; return c.u;
}
// runtime-g component select without dynamic extract
__device__ __forceinline__ float selg(v4f a, int g) {
    const float lo = (g & 1) ? a.y : a.x;
    const float hi = (g & 1) ? a.w : a.z;
    return (g & 2) ? hi : lo;
}
// pin fragment into AGPR half of the unified file (R12-proven: relieves the
// arch-VGPR grant AND is remat-proof)
#define PINA(x) asm volatile("" : "+a"(x))

// ---------------------------------------------------------------------------
// R13: MFMA GRU scan, 4 chains in ONE block, 1024 thr = 16 waves (4/SIMD).
// R12 post-mortem: step 1600 cyc = MFMA pipe ~624 (48 issues/SIMD x ~19 cyc,
// 4x N-waste structural) + ~880 tail (B-read wait, gate chain, barrier skew)
// that 2 waves/SIMD can't hide.  R13 splits hh/ih across wave-sets:
//  waves 0-7 (hh): 12 MFMA (Whh r,z,n; C-init = bhh+bih for r,z / bhh for n),
//                  gates, h-writes.  n-gate's bih kept in a scalar reg
//                  (outside the r-multiply - cannot be folded into C).
//  waves 8-15 (ih): 12 MFMA (Wih, C=0) on !ux / 3 Wc-MFMAs on ux; write
//                  selg'd gi-triple to padded xchg; do the hs-flush in their
//                  idle window (off the gate critical path).
// Same pipe work, 2x waves to overlap the tail; +1 barrier, +3-float xchg.
// All frags AGPR-pinned; per-wave unified budget 128 at 16 waves -> arch ~65.
// ---------------------------------------------------------------------------
__global__
__attribute__((amdgpu_flat_work_group_size(1024, 1024)))
void gru_kernel(
    const float* __restrict__ px,
    const float* __restrict__ py,
    const float* __restrict__ vx,
    const float* __restrict__ vy,
    const float* __restrict__ Wemb,   // [128,4]
    const float* __restrict__ bemb,   // [128]
    const float* __restrict__ Wih,    // [384,128]
    const float* __restrict__ Whh,    // [384,128]
    const float* __restrict__ bih,    // [384]
    const float* __restrict__ bhh,    // [384]
    const int*   __restrict__ step_mask, // [16384]
    const int*   __restrict__ ctxp,      // [1]
    unsigned short* __restrict__ hs)     // [4*16384*128] f16-bits staging
{
    const int tid  = threadIdx.x;
    const int w    = tid >> 6;          // wave 0..15
    const int wm   = w & 7;             // row-block 0..7 (k = 16wm..16wm+15)
    const int isI  = (w >= 8);          // ih wave-set
    const int lane = tid & 63;
    const int m    = lane & 15;         // A-frag row within tile
    const int q8   = (lane >> 4) * 8;   // A/B k-offset
    const int qq4  = (lane >> 4) * 4;   // D row-block
    const int cme  = lane & 3;          // chain
    const int gme  = (lane >> 2) & 3;   // replica -> row within D block
    const int kme  = 16 * wm + qq4 + gme;

    __shared__ alignas(16) _Float16 h2L[2][4][160];      // padded c-stride
    __shared__ alignas(16) _Float16 hringL[32][4][136];  // padded history
    __shared__ float xchgL[8][3][65];                    // gi exchange (pad 65)
    __shared__ alignas(16) uint4 xpadL[256][4];          // [x0..x3,1,0,0,0] f16
    __shared__ int   uxbuf[256];
    __shared__ float WembL[512];
    __shared__ float bembL[128];
    __shared__ alignas(16) float Wc4[384][4];
    __shared__ float bfoldL[384];                        // Wih·bemb (no bih)

    // ---- A-frags: 3 tiles (r,z,n of my matrix) x 4 K-frags ----
    v8h fr0, fr1, fr2, fr3, fz0, fz1, fz2, fz3, fn0, fn1, fn2, fn3;
    {
        const float* M = isI ? Wih : Whh;
        const float* pr = M + (size_t)(      16 * wm + m) * 128 + q8;
        const float* pz = M + (size_t)(128 + 16 * wm + m) * 128 + q8;
        const float* pn = M + (size_t)(256 + 16 * wm + m) * 128 + q8;
        fr0 = cvt8(pr); fr1 = cvt8(pr + 32); fr2 = cvt8(pr + 64); fr3 = cvt8(pr + 96);
        fz0 = cvt8(pz); fz1 = cvt8(pz + 32); fz2 = cvt8(pz + 64); fz3 = cvt8(pz + 96);
        fn0 = cvt8(pn); fn1 = cvt8(pn + 32); fn2 = cvt8(pn + 64); fn3 = cvt8(pn + 96);
    }
    PINA(fr0); PINA(fr1); PINA(fr2); PINA(fr3);
    PINA(fz0); PINA(fz1); PINA(fz2); PINA(fz3);
    PINA(fn0); PINA(fn1); PINA(fn2); PINA(fn3);

    // hh C-init: r,z get bhh+bih (pure sigmoid sums); n gets bhh only.
    v4f cR = {0.f, 0.f, 0.f, 0.f}, cZ = cR, cN = cR;
    float bin_me = 0.f;
    if (!isI) {
        const int rB = 16 * wm + qq4;
        cR = (v4f){ bhh[rB]   + bih[rB],   bhh[rB+1] + bih[rB+1],
                    bhh[rB+2] + bih[rB+2], bhh[rB+3] + bih[rB+3] };
        cZ = (v4f){ bhh[128+rB]   + bih[128+rB],   bhh[128+rB+1] + bih[128+rB+1],
                    bhh[128+rB+2] + bih[128+rB+2], bhh[128+rB+3] + bih[128+rB+3] };
        cN = (v4f){ bhh[256+rB], bhh[256+rB+1], bhh[256+rB+2], bhh[256+rB+3] };
        bin_me = bih[256 + kme];
    }

    if (tid < 512) WembL[tid] = Wemb[tid];
    if (tid < 128) bembL[tid] = bemb[tid];
    for (int i = tid; i < 2 * 4 * 160; i += 1024) ((_Float16*)h2L)[i] = (_Float16)0.f;
    __syncthreads();
    // folded embed: Wc[g] = Wih[g]·Wemb, bfold[g] = Wih[g]·bemb  (NO bih)
    if (tid < 384) {
        const float* wr = Wih + (size_t)tid * 128;
        float c0 = 0.f, c1 = 0.f, c2 = 0.f, c3 = 0.f, cb = 0.f;
        #pragma unroll 4
        for (int j = 0; j < 128; ++j) {
            const float wv = wr[j];
            const float4 e = *(const float4*)&WembL[j * 4];
            c0 = fmaf(wv, e.x, c0); c1 = fmaf(wv, e.y, c1);
            c2 = fmaf(wv, e.z, c2); c3 = fmaf(wv, e.w, c3);
            cb = fmaf(wv, bembL[j], cb);
        }
        Wc4[tid][0] = c0; Wc4[tid][1] = c1; Wc4[tid][2] = c2; Wc4[tid][3] = c3;
        bfoldL[tid] = cb;
    }
    __syncthreads();
    // Wc A-frags (ih waves only): k=0..3 = Wc row, k=4 = bemb-fold, rest 0
    v8h wcr = {}, wcz = {}, wcn = {};
    if (isI && lane < 16) {
        wcr[0] = (_Float16)Wc4[      16*wm + m][0]; wcr[1] = (_Float16)Wc4[      16*wm + m][1];
        wcr[2] = (_Float16)Wc4[      16*wm + m][2]; wcr[3] = (_Float16)Wc4[      16*wm + m][3];
        wcr[4] = (_Float16)bfoldL[      16*wm + m];
        wcz[0] = (_Float16)Wc4[128 + 16*wm + m][0]; wcz[1] = (_Float16)Wc4[128 + 16*wm + m][1];
        wcz[2] = (_Float16)Wc4[128 + 16*wm + m][2]; wcz[3] = (_Float16)Wc4[128 + 16*wm + m][3];
        wcz[4] = (_Float16)bfoldL[128 + 16*wm + m];
        wcn[0] = (_Float16)Wc4[256 + 16*wm + m][0]; wcn[1] = (_Float16)Wc4[256 + 16*wm + m][1];
        wcn[2] = (_Float16)Wc4[256 + 16*wm + m][2]; wcn[3] = (_Float16)Wc4[256 + 16*wm + m][3];
        wcn[4] = (_Float16)bfoldL[256 + 16*wm + m];
    }
    if (isI) { PINA(wcr); PINA(wcz); PINA(wcn); }

    const int ctxm = (ctxp[0] < 1) ? 1 : ctxp[0];
    float hold1 = 0.f;                  // hh: my (cme,kme) h state
    const v4f zc = {0.f, 0.f, 0.f, 0.f};

    for (int t0 = 0; t0 < TLEN; t0 += 256) {
        // prefetch x (f16, 1.0 pad at k=4) + use_x flags
        {
            const int t = tid >> 2, c = tid & 3;
            const int gt = t0 + t;
            const float* xa = (c == 0) ? px : (c == 1) ? py : (c == 2) ? vx : vy;
            uint4 u;
            u.x = packh2(xa[gt],            xa[TLEN + gt]);
            u.y = packh2(xa[2 * TLEN + gt], xa[3 * TLEN + gt]);
            u.z = packh2(1.f, 0.f);
            u.w = 0u;
            xpadL[t][c] = u;
        }
        if (tid < 256) {
            const int gt = t0 + tid;
            uxbuf[tid] = ((gt < ctxm) || (step_mask[gt] == 0)) ? 1 : 0;
        }
        __syncthreads();
        for (int tt = 0; tt < 256; ++tt) {
            const int gt  = t0 + tt;
            const int ux  = __builtin_amdgcn_readfirstlane(uxbuf[tt]);
            const int cur = gt & 1, nxt = cur ^ 1;
            v4f aR, aZ, aN;
            if (!isI) {
                const uint4* hq = (const uint4*)&h2L[cur][cme][0];
                U4H8 b0, b1, b2, b3;
                b0.u = hq[ 0 + (lane >> 4)];
                b1.u = hq[ 4 + (lane >> 4)];
                b2.u = hq[ 8 + (lane >> 4)];
                b3.u = hq[12 + (lane >> 4)];
                aR = __builtin_amdgcn_mfma_f32_16x16x32_f16(fr0, b0.h, cR, 0, 0, 0);
                aR = __builtin_amdgcn_mfma_f32_16x16x32_f16(fr1, b1.h, aR, 0, 0, 0);
                aR = __builtin_amdgcn_mfma_f32_16x16x32_f16(fr2, b2.h, aR, 0, 0, 0);
                aR = __builtin_amdgcn_mfma_f32_16x16x32_f16(fr3, b3.h, aR, 0, 0, 0);
                aZ = __builtin_amdgcn_mfma_f32_16x16x32_f16(fz0, b0.h, cZ, 0, 0, 0);
                aZ = __builtin_amdgcn_mfma_f32_16x16x32_f16(fz1, b1.h, aZ, 0, 0, 0);
                aZ = __builtin_amdgcn_mfma_f32_16x16x32_f16(fz2, b2.h, aZ, 0, 0, 0);
                aZ = __builtin_amdgcn_mfma_f32_16x16x32_f16(fz3, b3.h, aZ, 0, 0, 0);
                aN = __builtin_amdgcn_mfma_f32_16x16x32_f16(fn0, b0.h, cN, 0, 0, 0);
                aN = __builtin_amdgcn_mfma_f32_16x16x32_f16(fn1, b1.h, aN, 0, 0, 0);
                aN = __builtin_amdgcn_mfma_f32_16x16x32_f16(fn2, b2.h, aN, 0, 0, 0);
                aN = __builtin_amdgcn_mfma_f32_16x16x32_f16(fn3, b3.h, aN, 0, 0, 0);
            } else if (!ux) {
                const uint4* hq = (const uint4*)&h2L[cur][cme][0];
                U4H8 b0, b1, b2, b3;
                b0.u = hq[ 0 + (lane >> 4)];
                b1.u = hq[ 4 + (lane >> 4)];
                b2.u = hq[ 8 + (lane >> 4)];
                b3.u = hq[12 + (lane >> 4)];
                aR = __builtin_amdgcn_mfma_f32_16x16x32_f16(fr0, b0.h, zc, 0, 0, 0);
                aR = __builtin_amdgcn_mfma_f32_16x16x32_f16(fr1, b1.h, aR, 0, 0, 0);
                aR = __builtin_amdgcn_mfma_f32_16x16x32_f16(fr2, b2.h, aR, 0, 0, 0);
                aR = __builtin_amdgcn_mfma_f32_16x16x32_f16(fr3, b3.h, aR, 0, 0, 0);
                aZ = __builtin_amdgcn_mfma_f32_16x16x32_f16(fz0, b0.h, zc, 0, 0, 0);
                aZ = __builtin_amdgcn_mfma_f32_16x16x32_f16(fz1, b1.h, aZ, 0, 0, 0);
                aZ = __builtin_amdgcn_mfma_f32_16x16x32_f16(fz2, b2.h, aZ, 0, 0, 0);
                aZ = __builtin_amdgcn_mfma_f32_16x16x32_f16(fz3, b3.h, aZ, 0, 0, 0);
                aN = __builtin_amdgcn_mfma_f32_16x16x32_f16(fn0, b0.h, zc, 0, 0, 0);
                aN = __builtin_amdgcn_mfma_f32_16x16x32_f16(fn1, b1.h, aN, 0, 0, 0);
                aN = __builtin_amdgcn_mfma_f32_16x16x32_f16(fn2, b2.h, aN, 0, 0, 0);
                aN = __builtin_amdgcn_mfma_f32_16x16x32_f16(fn3, b3.h, aN, 0, 0, 0);
            } else {
                U4H8 xb;
                xb.u = xpadL[tt][cme];
                if (lane >= 16) { xb.u.x = 0u; xb.u.y = 0u; xb.u.z = 0u; xb.u.w = 0u; }
                aR = __builtin_amdgcn_mfma_f32_16x16x32_f16(wcr, xb.h, zc, 0, 0, 0);
                aZ = __builtin_amdgcn_mfma_f32_16x16x32_f16(wcz, xb.h, zc, 0, 0, 0);
                aN = __builtin_amdgcn_mfma_f32_16x16x32_f16(wcn, xb.h, zc, 0, 0, 0);
            }
            if (isI) {
                xchgL[wm][0][lane] = selg(aR, gme);
                xchgL[wm][1][lane] = selg(aZ, gme);
                xchgL[wm][2][lane] = selg(aN, gme);
            }
            __syncthreads();   // barrier 1: gi published
            if (!isI) {
                const float gir = xchgL[wm][0][lane];
                const float giz = xchgL[wm][1][lane];
                const float gin = xchgL[wm][2][lane];
                const float ghr = selg(aR, gme);   // incl bhh+bih
                const float ghz = selg(aZ, gme);   // incl bhh+bih
                const float ghn = selg(aN, gme);   // incl bhh only
                const float r    = 1.f / (1.f + __expf(-(gir + ghr)));
                const float z    = 1.f / (1.f + __expf(-(giz + ghz)));
                const float npre = fmaf(r, ghn, gin + bin_me);
                const float e2   = __expf(2.f * npre);
                const float n    = 1.f - 2.f / (e2 + 1.f);       // tanh
                const float hnew = fmaf(z, hold1 - n, n);        // (1-z)n + z h
                hold1 = hnew;
                h2L[nxt][cme][kme]        = (_Float16)hnew;
                hringL[gt & 31][cme][kme] = (_Float16)hnew;
            } else if ((gt & 15) == 1 && gt > 16 && tid < 768) {
                // hs flush in ih idle window (disjoint ring half)
                const int u = tid - 512;
                const int G = (gt >> 4) - 1;
                #pragma unroll
                for (int j = 0; j < 4; ++j) {
                    const int v  = u + (j << 8);
                    const int c  = v >> 8, sl = (v >> 4) & 15, g = v & 15;
                    ((uint4*)hs)[(size_t)(c * TLEN + (G << 4) + sl) * 16 + g] =
                        *(const uint4*)&hringL[((G & 1) << 4) + sl][c][g << 3];
                }
            }
            __syncthreads();   // barrier 2: h_t published
        }
    }
    // final flush: steps 16368..16383 (slots 16..31)
    if (tid < 256) {
        #pragma unroll
        for (int j = 0; j < 4; ++j) {
            const int v  = tid + (j << 8);
            const int c  = v >> 8, sl = (v >> 4) & 15, g = v & 15;
            ((uint4*)hs)[(size_t)(c * TLEN + 16368 + sl) * 16 + g] =
                *(const uint4*)&hringL[16 + sl][c][g << 3];
        }
    }
}

// ---------------------------------------------------------------------------
// Head MLP over all 65536 hidden states (unchanged).
// ---------------------------------------------------------------------------
__global__ __launch_bounds__(64) void head_kernel(
    const float*  __restrict__ W1,
    const float*  __restrict__ b1,
    const float*  __restrict__ W2,
    const float*  __restrict__ b2,
    const float*  __restrict__ W3,
    const float*  __restrict__ b3,
    const __half* __restrict__ hs,
    float*        __restrict__ out)
{
    __shared__ float W1L[64 * 128];
    __shared__ float W2L[64 * 64];
    __shared__ float W3L[2 * 64];
    __shared__ float b1L[64], b2L[64], b3L[2];
    __shared__ float y1L[64 * 65];

    const int tid = threadIdx.x;
    {
        float4* dst1 = (float4*)W1L; const float4* src1 = (const float4*)W1;
        for (int i = tid; i < 2048; i += 64) dst1[i] = src1[i];
        float4* dst2 = (float4*)W2L; const float4* src2 = (const float4*)W2;
        for (int i = tid; i < 1024; i += 64) dst2[i] = src2[i];
        if (tid < 32) ((float4*)W3L)[tid] = ((const float4*)W3)[tid];
        b1L[tid] = b1[tid];
        b2L[tid] = b2[tid];
        if (tid < 2) b3L[tid] = b3[tid];
    }
    __syncthreads();

    const int row = blockIdx.x * 64 + tid;
    float h[128];
    {
        const uint4* hp = (const uint4*)(hs + (size_t)row * HD);
        #pragma unroll
        for (int c = 0; c < 16; ++c) {
            uint4 q = hp[c];
            const __half2* hh = (const __half2*)&q;
            #pragma unroll
            for (int d = 0; d < 4; ++d) {
                const float2 f = __half22float2(hh[d]);
                h[c*8 + d*2 + 0] = f.x;
                h[c*8 + d*2 + 1] = f.y;
            }
        }
    }
    for (int l = 0; l < 64; ++l) {
        float a0 = b1L[l], a1 = 0.f;
        #pragma unroll
        for (int j = 0; j < 128; j += 4) {
            const float4 wv = *(const float4*)&W1L[l*128 + j];
            a0 = fmaf(wv.x, h[j+0], a0);
            a1 = fmaf(wv.y, h[j+1], a1);
            a0 = fmaf(wv.z, h[j+2], a0);
            a1 = fmaf(wv.w, h[j+3], a1);
        }
        const float acc = a0 + a1;
        y1L[tid * 65 + l] = (acc > 0.f) ? acc : (__expf(acc) - 1.f);
    }
    float y30 = b3L[0], y31 = b3L[1];
    for (int l = 0; l < 64; ++l) {
        float a0 = b2L[l], a1 = 0.f;
        const int yb = tid * 65;
        #pragma unroll
        for (int j = 0; j < 64; j += 4) {
            const float4 wv = *(const float4*)&W2L[l*64 + j];
            a0 = fmaf(wv.x, y1L[yb + j+0], a0);
            a1 = fmaf(wv.y, y1L[yb + j+1], a1);
            a0 = fmaf(wv.z, y1L[yb + j+2], a0);
            a1 = fmaf(wv.w, y1L[yb + j+3], a1);
        }
        const float acc = a0 + a1;
        const float v = (acc > 0.f) ? acc : (__expf(acc) - 1.f);
        y30 = fmaf(W3L[l],      v, y30);
        y31 = fmaf(W3L[64 + l], v, y31);
    }
    out[row]            = y30;
    out[4 * TLEN + row] = y31;
}

extern "C" void kernel_launch(void* const* d_in, const int* in_sizes, int n_in,
                              void* d_out, int out_size, void* d_ws, size_t ws_size,
                              hipStream_t stream) {
    const float* px   = (const float*)d_in[0];
    const float* py   = (const float*)d_in[1];
    const float* vx   = (const float*)d_in[2];
    const float* vy   = (const float*)d_in[3];
    const float* Wemb = (const float*)d_in[4];
    const float* bemb = (const float*)d_in[5];
    const float* Wih  = (const float*)d_in[6];
    const float* Whh  = (const float*)d_in[7];
    const float* bih  = (const float*)d_in[8];
    const float* bhh  = (const float*)d_in[9];
    const float* W1   = (const float*)d_in[10];
    const float* b1   = (const float*)d_in[11];
    const float* W2   = (const float*)d_in[12];
    const float* b2   = (const float*)d_in[13];
    const float* W3   = (const float*)d_in[14];
    const float* b3   = (const float*)d_in[15];
    const int* step_mask = (const int*)d_in[16];
    const int* ctx       = (const int*)d_in[17];
    unsigned short* hs = (unsigned short*)d_ws;  // 4*16384*128 f16-bits = 16.8 MB
    float* out = (float*)d_out;                  // f32, [2][4][16384] flat

    hipLaunchKernelGGL(gru_kernel, dim3(1), dim3(1024), 0, stream,
                       px, py, vx, vy, Wemb, bemb, Wih, Whh, bih, bhh,
                       step_mask, ctx, hs);
    hipLaunchKernelGGL(head_kernel, dim3(1024), dim3(64), 0, stream,
                       W1, b1, W2, b2, W3, b3, (const __half*)hs, out);
}